// Round 5
// baseline (181.334 us; speedup 1.0000x reference)
//
#include <hip/hip_runtime.h>

typedef unsigned short u16;
typedef unsigned int u32;
typedef __bf16 bf16x8 __attribute__((ext_vector_type(8)));
typedef float f32x4 __attribute__((ext_vector_type(4)));

#define GRID_G 96
#define DMODEL 512
#define NTOK (GRID_G * GRID_G)

__device__ __forceinline__ u16 f2bf(float f) {
  u32 u = __builtin_bit_cast(u32, f);
  u += 0x7fffu + ((u >> 16) & 1u);   // round-to-nearest-even
  return (u16)(u >> 16);
}
__device__ __forceinline__ void unpack8(uint4 u, float* f) {
  f[0] = __builtin_bit_cast(float, u.x << 16);
  f[1] = __builtin_bit_cast(float, u.x & 0xffff0000u);
  f[2] = __builtin_bit_cast(float, u.y << 16);
  f[3] = __builtin_bit_cast(float, u.y & 0xffff0000u);
  f[4] = __builtin_bit_cast(float, u.z << 16);
  f[5] = __builtin_bit_cast(float, u.z & 0xffff0000u);
  f[6] = __builtin_bit_cast(float, u.w << 16);
  f[7] = __builtin_bit_cast(float, u.w & 0xffff0000u);
}
// gelu (tanh form, stable): max dev vs erf-gelu ~3e-4 — far under threshold
__device__ __forceinline__ float gelu_fast(float x) {
  float y = 0.7978845608f * (x + 0.044715f * x * x * x);
  float a = fabsf(y);
  float e = __expf(-2.0f * a);
  float th = (1.0f - e) / (1.0f + e);
  th = __builtin_copysignf(th, y);
  return 0.5f * x * (1.0f + th);
}

// ---------------- transpose f32 [R][C] -> bf16 [C][R] ----------------
__global__ __launch_bounds__(256) void k_transpose_bf16(
    const float* __restrict__ src, u16* __restrict__ dst, int R, int C) {
  __shared__ float tile[32][33];
  int bx = blockIdx.x * 32, by = blockIdx.y * 32;
  int tx = threadIdx.x & 31, ty = threadIdx.x >> 5;
#pragma unroll
  for (int i = 0; i < 4; ++i) {
    int r = ty + i * 8;
    tile[r][tx] = src[(size_t)(by + r) * C + (bx + tx)];
  }
  __syncthreads();
#pragma unroll
  for (int i = 0; i < 4; ++i) {
    int c = ty + i * 8;
    dst[(size_t)(bx + c) * R + (by + tx)] = f2bf(tile[tx][c]);
  }
}

__global__ __launch_bounds__(256) void k_transpose4(
    const float* __restrict__ s0, const float* __restrict__ s1,
    const float* __restrict__ s2, const float* __restrict__ s3,
    u16* __restrict__ d0, u16* __restrict__ d1,
    u16* __restrict__ d2, u16* __restrict__ d3) {
  __shared__ float tile[32][33];
  const float* src = blockIdx.z == 0 ? s0 : blockIdx.z == 1 ? s1 : blockIdx.z == 2 ? s2 : s3;
  u16* dst = blockIdx.z == 0 ? d0 : blockIdx.z == 1 ? d1 : blockIdx.z == 2 ? d2 : d3;
  int bx = blockIdx.x * 32, by = blockIdx.y * 32;
  int tx = threadIdx.x & 31, ty = threadIdx.x >> 5;
#pragma unroll
  for (int i = 0; i < 4; ++i) {
    int r = ty + i * 8;
    tile[r][tx] = src[(size_t)(by + r) * 512 + (bx + tx)];
  }
  __syncthreads();
#pragma unroll
  for (int i = 0; i < 4; ++i) {
    int c = ty + i * 8;
    dst[(size_t)(bx + c) * 512 + (by + tx)] = f2bf(tile[tx][c]);
  }
}

__global__ __launch_bounds__(256) void k_concat3(
    const float* __restrict__ a, const float* __restrict__ b,
    const float* __restrict__ c, float* __restrict__ o) {
  int i = blockIdx.x * 256 + threadIdx.x;  // grid 6
  if (i < 512) o[i] = a[i];
  else if (i < 1024) o[i] = b[i - 512];
  else o[i] = c[i - 1024];
}

// ---------------- LayerNorm f32 -> bf16, D=512, one wave per row ----------------
__global__ __launch_bounds__(256) void k_layernorm_bf16(
    const float* __restrict__ x, const float* __restrict__ g,
    const float* __restrict__ b, u16* __restrict__ out) {
  int tid = threadIdx.x, wid = tid >> 6, lane = tid & 63;
  int row = blockIdx.x * 4 + wid;
  const float* xr = x + (size_t)row * DMODEL;
  float4 v0 = *(const float4*)(xr + lane * 4);
  float4 v1 = *(const float4*)(xr + 256 + lane * 4);
  float s = v0.x + v0.y + v0.z + v0.w + v1.x + v1.y + v1.z + v1.w;
  float sq = v0.x * v0.x + v0.y * v0.y + v0.z * v0.z + v0.w * v0.w +
             v1.x * v1.x + v1.y * v1.y + v1.z * v1.z + v1.w * v1.w;
#pragma unroll
  for (int m = 1; m < 64; m <<= 1) {
    s += __shfl_xor(s, m);
    sq += __shfl_xor(sq, m);
  }
  float mean = s * (1.0f / DMODEL);
  float rstd = rsqrtf(sq * (1.0f / DMODEL) - mean * mean + 1e-5f);
  float4 ga = *(const float4*)(g + lane * 4);
  float4 gb = *(const float4*)(g + 256 + lane * 4);
  float4 ba = *(const float4*)(b + lane * 4);
  float4 bb = *(const float4*)(b + 256 + lane * 4);
  ushort4 o0, o1;
  o0.x = f2bf((v0.x - mean) * rstd * ga.x + ba.x);
  o0.y = f2bf((v0.y - mean) * rstd * ga.y + ba.y);
  o0.z = f2bf((v0.z - mean) * rstd * ga.z + ba.z);
  o0.w = f2bf((v0.w - mean) * rstd * ga.w + ba.w);
  o1.x = f2bf((v1.x - mean) * rstd * gb.x + bb.x);
  o1.y = f2bf((v1.y - mean) * rstd * gb.y + bb.y);
  o1.z = f2bf((v1.z - mean) * rstd * gb.z + bb.z);
  o1.w = f2bf((v1.w - mean) * rstd * gb.w + bb.w);
  u16* op = out + (size_t)row * DMODEL;
  *(ushort4*)(op + lane * 4) = o0;
  *(ushort4*)(op + 256 + lane * 4) = o1;
}

// ---------------- local attention: one wave per token ----------------
__global__ __launch_bounds__(256) void k_attn(
    const u16* __restrict__ q, const u16* __restrict__ kk,
    const u16* __restrict__ vv, const int* __restrict__ gpos,
    u16* __restrict__ out) {
  int tid = threadIdx.x, wid = tid >> 6, lane = tid & 63;
  int n = blockIdx.x * 4 + wid;
  int px = gpos[2 * n], py = gpos[2 * n + 1];
  float qf[8];
  unpack8(*(const uint4*)(q + (size_t)n * DMODEL + lane * 8), qf);
  float sc[24];
  int nid[24];
  bool ok[24];
#pragma unroll
  for (int j = 0; j < 24; ++j) {
    int jj = j < 12 ? j : j + 1;           // skip (0,0)
    int dx = jj / 5 - 2, dy = jj % 5 - 2;
    int nx = px + dx, ny = py + dy;
    bool val = (nx >= 0) && (nx < GRID_G) && (ny >= 0) && (ny < GRID_G);
    int id = val ? nx * GRID_G + ny : 0;
    ok[j] = val;
    nid[j] = id;
    float kf[8];
    unpack8(*(const uint4*)(kk + (size_t)id * DMODEL + lane * 8), kf);
    float p = 0.f;
#pragma unroll
    for (int e = 0; e < 8; ++e) p += qf[e] * kf[e];
#pragma unroll
    for (int m = 1; m < 64; m <<= 1) p += __shfl_xor(p, m);
    sc[j] = p * 0.04419417382415922f;  // 1/sqrt(512)
  }
  float mx = -3.0e38f;
#pragma unroll
  for (int j = 0; j < 24; ++j)
    if (ok[j]) mx = fmaxf(mx, sc[j]);
  float wsum = 0.f, w[24];
#pragma unroll
  for (int j = 0; j < 24; ++j) {
    w[j] = ok[j] ? expf(sc[j] - mx) : 0.f;
    wsum += w[j];
  }
  float inv = 1.0f / wsum;
  float acc[8] = {0, 0, 0, 0, 0, 0, 0, 0};
#pragma unroll
  for (int j = 0; j < 24; ++j) {
    float vf[8];
    unpack8(*(const uint4*)(vv + (size_t)nid[j] * DMODEL + lane * 8), vf);
    float wj = w[j];
#pragma unroll
    for (int e = 0; e < 8; ++e) acc[e] += wj * vf[e];
  }
  uint4 o;
  o.x = (u32)f2bf(acc[0] * inv) | ((u32)f2bf(acc[1] * inv) << 16);
  o.y = (u32)f2bf(acc[2] * inv) | ((u32)f2bf(acc[3] * inv) << 16);
  o.z = (u32)f2bf(acc[4] * inv) | ((u32)f2bf(acc[5] * inv) << 16);
  o.w = (u32)f2bf(acc[6] * inv) | ((u32)f2bf(acc[7] * inv) << 16);
  *(uint4*)(out + (size_t)n * DMODEL + lane * 8) = o;
}

// ============ small MFMA GEMM (128x128, 2-phase dbuf) — for N=512 GEMMs ============
// EPI 1: out_f32 = res + acc + bias
template <int EPI>
__global__ __launch_bounds__(256, 2) void k_gemm(
    const u16* __restrict__ A, const u16* __restrict__ Bt,
    const float* __restrict__ bias, const float* __restrict__ res,
    float* __restrict__ outF, u16* __restrict__ outB,
    int M, int N, int K, int tiles_n) {
  __shared__ u16 lds[32768];
  const int t = threadIdx.x, wid = t >> 6, lane = t & 63;
  const int nwg = gridDim.x, bid = blockIdx.x;
  const int l = ((bid & 7) * (nwg >> 3)) + (bid >> 3);
  const int bM = (l / tiles_n) * 128, bN = (l % tiles_n) * 128;
  const int wr = wid >> 1, wc = wid & 1, lr = lane & 15, lg = lane >> 4;

  const int rs = lane >> 3;
  const int cl = (lane & 7) ^ rs;
  const u16* gA[4];
  const u16* gB[4];
  int dstL[4];
#pragma unroll
  for (int j = 0; j < 4; ++j) {
    int r = wid * 32 + j * 8 + rs;
    gA[j] = A + (size_t)(bM + r) * K + cl * 8;
    gB[j] = Bt + (size_t)(bN + r) * K + cl * 8;
    dstL[j] = wid * 2048 + j * 512;
  }

#define STAGE(BUF, KOFF)                                                              \
  {                                                                                   \
    _Pragma("unroll") for (int j = 0; j < 4; ++j) {                                   \
      __builtin_amdgcn_global_load_lds(                                               \
          (const __attribute__((address_space(1))) void*)(gA[j] + (KOFF)),            \
          (__attribute__((address_space(3))) void*)(lds + (BUF)*16384 + dstL[j]),     \
          16, 0, 0);                                                                  \
      __builtin_amdgcn_global_load_lds(                                               \
          (const __attribute__((address_space(1))) void*)(gB[j] + (KOFF)),            \
          (__attribute__((address_space(3))) void*)(lds + (BUF)*16384 + 8192 + dstL[j]), \
          16, 0, 0);                                                                  \
    }                                                                                 \
  }

  const int offA0 = (wr * 64 + lr) * 64 + ((0 + lg) ^ (lr & 7)) * 8;
  const int offA1 = (wr * 64 + lr) * 64 + ((4 + lg) ^ (lr & 7)) * 8;
  const int offB0 = (wc * 64 + lr) * 64 + ((0 + lg) ^ (lr & 7)) * 8;
  const int offB1 = (wc * 64 + lr) * 64 + ((4 + lg) ^ (lr & 7)) * 8;

  f32x4 acc[4][4];
#pragma unroll
  for (int i = 0; i < 4; ++i)
#pragma unroll
    for (int j = 0; j < 4; ++j) acc[i][j] = (f32x4){0.f, 0.f, 0.f, 0.f};

#define COMPUTE(BUF)                                                                  \
  {                                                                                   \
    _Pragma("unroll") for (int ks = 0; ks < 2; ++ks) {                                \
      const int oa = (BUF)*16384 + (ks ? offA1 : offA0);                              \
      const int ob = (BUF)*16384 + 8192 + (ks ? offB1 : offB0);                       \
      bf16x8 af[4], bfr[4];                                                           \
      _Pragma("unroll") for (int mt = 0; mt < 4; ++mt)                                \
          af[mt] = __builtin_bit_cast(bf16x8, *(const uint4*)(lds + oa + mt * 1024)); \
      _Pragma("unroll") for (int nt = 0; nt < 4; ++nt)                                \
          bfr[nt] = __builtin_bit_cast(bf16x8, *(const uint4*)(lds + ob + nt * 1024));\
      _Pragma("unroll") for (int mt = 0; mt < 4; ++mt)                                \
          _Pragma("unroll") for (int nt = 0; nt < 4; ++nt)                            \
              acc[mt][nt] = __builtin_amdgcn_mfma_f32_16x16x32_bf16(                  \
                  af[mt], bfr[nt], acc[mt][nt], 0, 0, 0);                             \
    }                                                                                 \
  }

  const int nk = K >> 6;
  STAGE(0, 0);
  __syncthreads();
  int koff = 64;
  for (int tt = 0; tt < nk; tt += 2) {
    if (tt + 1 < nk) STAGE(1, koff);
    COMPUTE(0);
    __syncthreads();
    if (tt + 2 < nk) STAGE(0, koff + 64);
    COMPUTE(1);
    __syncthreads();
    koff += 128;
  }
#undef STAGE
#undef COMPUTE

#pragma unroll
  for (int mt = 0; mt < 4; ++mt) {
#pragma unroll
    for (int nt = 0; nt < 4; ++nt) {
      int col = bN + wc * 64 + nt * 16 + lr;
      float bc = bias[col];
      int row0 = bM + wr * 64 + mt * 16 + lg * 4;
#pragma unroll
      for (int r = 0; r < 4; ++r) {
        float val = acc[mt][nt][r] + bc;
        size_t off = (size_t)(row0 + r) * N + col;
        if constexpr (EPI == 1) {
          outF[off] = res[off] + val;
        } else {
          outB[off] = f2bf(val);
        }
      }
    }
  }
}

// ============ BIG MFMA GEMM: 256x256 tile, 8 waves, 4-band phases, counted vmcnt ============
// Template per cdna_hip_programming.md §5 (T2+T3+T4+T5), adapted to XOR-chunk swizzle.
// EPI 2: out_bf16 = gelu(acc + bias)       (row-major [*, N])
// EPI 3: QKV segmented out_bf16[seg][row][col&511]
#define BARR { __builtin_amdgcn_s_barrier(); __builtin_amdgcn_sched_barrier(0); }
#define WAITV0 asm volatile("s_waitcnt vmcnt(0)" ::: "memory");
#define WAITV2 asm volatile("s_waitcnt vmcnt(2)" ::: "memory");
#define WAITV4 asm volatile("s_waitcnt vmcnt(4)" ::: "memory");

template <int EPI>
__global__ __launch_bounds__(512, 2) void k_gemm_big(
    const u16* __restrict__ A, const u16* __restrict__ Bt,
    const float* __restrict__ bias, u16* __restrict__ outB,
    int K, int N, int tiles_n) {
  __shared__ u16 lds[65536];  // 128KB: buf c at c*32768; A [256][64] at +0, B at +16384
  const int t = threadIdx.x, wid = t >> 6, lane = t & 63;
  const int wr = wid >> 2, wc = wid & 3;   // 2M x 4N waves
  const int lr = lane & 15, lg = lane >> 4;
  const int nwg = gridDim.x, bid = blockIdx.x;
  const int qq = nwg >> 3, rr = nwg & 7;
  const int xcd = bid & 7, seq = bid >> 3;
  const int l = (xcd < rr ? xcd * (qq + 1) : rr * (qq + 1) + (xcd - rr) * qq) + seq;
  const int bM = (l / tiles_n) * 256, bN = (l % tiles_n) * 256;

  // staging: per-thread source row/chunk (pre-swizzled: cl = chunk ^ (row&7))
  const int srow = wid * 8 + (lane >> 3);
  const int cl = (lane & 7) ^ (lane >> 3);
  const u16* pA = A + (size_t)(bM + srow) * K + cl * 8;
  const u16* pB = Bt + (size_t)(bN + srow) * K + cl * 8;
  const int dbase = wid * 512;  // + j*4096 + h*8192 (+16384 for B)

// stage one half-tile (128 rows) of A (BOFF=0) or B (BOFF=16384), 2 loads/thread
#define STG(C, BOFF, PTR, H, KT)                                                       \
  { _Pragma("unroll") for (int j = 0; j < 2; ++j)                                      \
      __builtin_amdgcn_global_load_lds(                                                \
        (const __attribute__((address_space(1))) void*)((PTR) + (size_t)((H)*128 + j*64) * K + (KT)), \
        (__attribute__((address_space(3))) void*)(lds + (C)*32768 + (BOFF) + (H)*8192 + dbase + j*4096), \
        16, 0, 0); }

  // ds_read swizzled chunk offsets (row&7 == lr&7 for all frag rows)
  const int swz0 = ((0 + lg) ^ (lr & 7)) * 8;
  const int swz1 = ((4 + lg) ^ (lr & 7)) * 8;

  f32x4 acc[4][2][4];
#pragma unroll
  for (int q = 0; q < 4; ++q)
#pragma unroll
    for (int u = 0; u < 2; ++u)
#pragma unroll
      for (int nt = 0; nt < 4; ++nt) acc[q][u][nt] = (f32x4){0.f, 0.f, 0.f, 0.f};

  bf16x8 b[4][2], a[2][2];

#define PH_READ_B(C)                                                                   \
  { _Pragma("unroll") for (int nt = 0; nt < 4; ++nt) {                                 \
      const u16* bb = lds + (C)*32768 + 16384 + (wc * 64 + nt * 16 + lr) * 64;         \
      b[nt][0] = __builtin_bit_cast(bf16x8, *(const uint4*)(bb + swz0));               \
      b[nt][1] = __builtin_bit_cast(bf16x8, *(const uint4*)(bb + swz1)); } }

#define PH_READ_A(C, Q)                                                                \
  { _Pragma("unroll") for (int u = 0; u < 2; ++u) {                                    \
      const u16* ab = lds + (C)*32768 + ((Q)*64 + wr * 32 + u * 16 + lr) * 64;         \
      a[u][0] = __builtin_bit_cast(bf16x8, *(const uint4*)(ab + swz0));                \
      a[u][1] = __builtin_bit_cast(bf16x8, *(const uint4*)(ab + swz1)); } }

#define PH_MFMA(Q)                                                                     \
  { __builtin_amdgcn_s_setprio(1);                                                     \
    _Pragma("unroll") for (int u = 0; u < 2; ++u)                                      \
    _Pragma("unroll") for (int nt = 0; nt < 4; ++nt) {                                 \
      acc[Q][u][nt] = __builtin_amdgcn_mfma_f32_16x16x32_bf16(a[u][0], b[nt][0], acc[Q][u][nt], 0, 0, 0); \
      acc[Q][u][nt] = __builtin_amdgcn_mfma_f32_16x16x32_bf16(a[u][1], b[nt][1], acc[Q][u][nt], 0, 0, 0); } \
    __builtin_amdgcn_s_setprio(0); }

// one K-tile = 4 band-phases; stages next tile's halves B0,B1,A0,A1 into buf C^1.
// vmcnt(4)@p1: cur A-h1 landed (collective at p1 barrier, read p2).
// vmcnt(2)@p3: next B0,B1,A0 landed (boundary).
#define TILE_BODY(TT, C)                                                               \
  {                                                                                    \
    const bool pre = (TT) + 1 < nk;                                                    \
    const int kn = ((TT) + 1) << 6;                                                    \
    PH_READ_B(C); PH_READ_A(C, 0);                                                     \
    if (pre) STG(C ^ 1, 16384, pB, 0, kn);                                             \
    BARR; PH_MFMA(0); BARR;                                                            \
    PH_READ_A(C, 1);                                                                   \
    if (pre) { STG(C ^ 1, 16384, pB, 1, kn); WAITV4; } else { WAITV0; }                \
    BARR; PH_MFMA(1); BARR;                                                            \
    PH_READ_A(C, 2);                                                                   \
    if (pre) STG(C ^ 1, 0, pA, 0, kn);                                                 \
    BARR; PH_MFMA(2); BARR;                                                            \
    PH_READ_A(C, 3);                                                                   \
    if (pre) { STG(C ^ 1, 0, pA, 1, kn); WAITV2; }                                     \
    BARR; PH_MFMA(3); BARR;                                                            \
  }

  // prologue: full tile 0 into buf 0
  STG(0, 16384, pB, 0, 0); STG(0, 16384, pB, 1, 0);
  STG(0, 0, pA, 0, 0);     STG(0, 0, pA, 1, 0);
  WAITV0;
  BARR;

  const int nk = K >> 6;  // even (8 or 32)
  for (int tt = 0; tt < nk; tt += 2) {
    TILE_BODY(tt, 0);
    TILE_BODY(tt + 1, 1);
  }
#undef TILE_BODY
#undef PH_MFMA
#undef PH_READ_A
#undef PH_READ_B
#undef STG

  // epilogue: D row = lg*4 + r, col = lr per 16x16 frag
#pragma unroll
  for (int q = 0; q < 4; ++q) {
#pragma unroll
    for (int u = 0; u < 2; ++u) {
#pragma unroll
      for (int nt = 0; nt < 4; ++nt) {
        int col = bN + wc * 64 + nt * 16 + lr;
        float bc = bias[col];
        int row0 = bM + q * 64 + wr * 32 + u * 16 + lg * 4;
#pragma unroll
        for (int r = 0; r < 4; ++r) {
          float val = acc[q][u][nt][r] + bc;
          if constexpr (EPI == 2) {
            outB[(size_t)(row0 + r) * N + col] = f2bf(gelu_fast(val));
          } else {  // EPI 3: segmented QKV
            int seg = col >> 9;
            size_t off = (size_t)seg * ((size_t)NTOK * DMODEL) +
                         (size_t)(row0 + r) * DMODEL + (col & 511);
            outB[off] = f2bf(val);
          }
        }
      }
    }
  }
}

// ---------------- workspace layout ----------------
extern "C" void kernel_launch(void* const* d_in, const int* in_sizes, int n_in,
                              void* d_out, int out_size, void* d_ws, size_t ws_size,
                              hipStream_t stream) {
  const float* x = (const float*)d_in[0];
  const int* gpos = (const int*)d_in[1];
  const float* Wq = (const float*)d_in[2];
  const float* bq = (const float*)d_in[3];
  const float* Wk = (const float*)d_in[4];
  const float* bk = (const float*)d_in[5];
  const float* Wv = (const float*)d_in[6];
  const float* bv = (const float*)d_in[7];
  const float* Wo = (const float*)d_in[8];
  const float* bo = (const float*)d_in[9];
  const float* g1 = (const float*)d_in[10];
  const float* b1 = (const float*)d_in[11];
  const float* g2 = (const float*)d_in[12];
  const float* b2 = (const float*)d_in[13];
  const float* W1 = (const float*)d_in[14];
  const float* bf1 = (const float*)d_in[15];
  const float* W2 = (const float*)d_in[16];
  const float* bf2 = (const float*)d_in[17];
  float* out = (float*)d_out;
  char* ws = (char*)d_ws;

  constexpr size_t SZ_W512 = (size_t)512 * 512 * 2;
  constexpr size_t SZ_W2048 = (size_t)512 * 2048 * 2;
  constexpr size_t SZ_ACT = (size_t)NTOK * 512 * 2;

  u16* WQT = (u16*)(ws + 0);                 // [1536][512] contiguous (Q,K,V)
  u16* WKT = (u16*)(ws + SZ_W512);
  u16* WVT = (u16*)(ws + 2 * SZ_W512);
  u16* WOT = (u16*)(ws + 3 * SZ_W512);
  u16* W1T = (u16*)(ws + 4 * SZ_W512);
  u16* W2T = (u16*)(ws + 4 * SZ_W512 + SZ_W2048);
  float* BCAT = (float*)(ws + 4 * SZ_W512 + 2 * SZ_W2048);  // 1536 f32
  char* actbase = ws + 4 * SZ_W512 + 2 * SZ_W2048 + 6144;
  u16* H = (u16*)(actbase);
  u16* Q = (u16*)(actbase + SZ_ACT);         // Q,K,V contiguous (fused epilogue)
  u16* KB = (u16*)(actbase + 2 * SZ_ACT);
  u16* VB = (u16*)(actbase + 3 * SZ_ACT);
  u16* H2 = (u16*)(actbase + 4 * SZ_ACT);
  u16* U = (u16*)(actbase);                  // [NTOK][2048] overlaps H,Q,K,V

  // weight prep
  k_transpose4<<<dim3(16, 16, 4), 256, 0, stream>>>(Wq, Wk, Wv, Wo, WQT, WKT, WVT, WOT);
  k_transpose_bf16<<<dim3(64, 16), 256, 0, stream>>>(W1, W1T, 512, 2048);
  k_transpose_bf16<<<dim3(16, 64), 256, 0, stream>>>(W2, W2T, 2048, 512);
  k_concat3<<<6, 256, 0, stream>>>(bq, bk, bv, BCAT);

  // LN1: x -> h
  k_layernorm_bf16<<<NTOK / 4, 256, 0, stream>>>(x, g1, b1, H);

  // fused QKV: [NTOK,1536] = H @ [Wq|Wk|Wv]^T   (256² tiles: 36x6 = 216 blocks)
  k_gemm_big<3><<<216, 512, 0, stream>>>(H, WQT, BCAT, Q, 512, 1536, 6);

  // local attention -> H (reuse)
  k_attn<<<NTOK / 4, 256, 0, stream>>>(Q, KB, VB, gpos, H);

  // y = x + attn @ Wo + bo  (f32, in d_out; 128² tiles: 288 blocks)
  k_gemm<1><<<288, 256, 0, stream>>>(H, WOT, bo, x, out, nullptr, NTOK, 512, 512, 4);

  // LN2: y -> h2
  k_layernorm_bf16<<<NTOK / 4, 256, 0, stream>>>(out, g2, b2, H2);

  // u = gelu(h2 @ W1 + bf1)   (256² tiles: 36x8 = 288 blocks)
  k_gemm_big<2><<<288, 512, 0, stream>>>(H2, W1T, bf1, U, 512, 2048, 8);

  // out = y + u @ W2 + bf2  (in-place residual; 128² tiles: 288 blocks)
  k_gemm<1><<<288, 256, 0, stream>>>(U, W2T, bf2, out, out, nullptr, NTOK, 512, 2048, 4);
}

// Round 6
// 164.916 us; speedup vs baseline: 1.0996x; 1.0996x over previous
//
#include <hip/hip_runtime.h>

typedef unsigned short u16;
typedef unsigned int u32;
typedef __bf16 bf16x8 __attribute__((ext_vector_type(8)));
typedef float f32x4 __attribute__((ext_vector_type(4)));

#define GRID_G 96
#define DMODEL 512
#define NTOK (GRID_G * GRID_G)

__device__ __forceinline__ u16 f2bf(float f) {
  u32 u = __builtin_bit_cast(u32, f);
  u += 0x7fffu + ((u >> 16) & 1u);   // round-to-nearest-even
  return (u16)(u >> 16);
}
__device__ __forceinline__ void unpack8(uint4 u, float* f) {
  f[0] = __builtin_bit_cast(float, u.x << 16);
  f[1] = __builtin_bit_cast(float, u.x & 0xffff0000u);
  f[2] = __builtin_bit_cast(float, u.y << 16);
  f[3] = __builtin_bit_cast(float, u.y & 0xffff0000u);
  f[4] = __builtin_bit_cast(float, u.z << 16);
  f[5] = __builtin_bit_cast(float, u.z & 0xffff0000u);
  f[6] = __builtin_bit_cast(float, u.w << 16);
  f[7] = __builtin_bit_cast(float, u.w & 0xffff0000u);
}
// gelu (tanh form, stable): max dev vs erf-gelu ~3e-4 — far under threshold
__device__ __forceinline__ float gelu_fast(float x) {
  float y = 0.7978845608f * (x + 0.044715f * x * x * x);
  float a = fabsf(y);
  float e = __expf(-2.0f * a);
  float th = (1.0f - e) / (1.0f + e);
  th = __builtin_copysignf(th, y);
  return 0.5f * x * (1.0f + th);
}

// ---------------- transpose f32 [R][C] -> bf16 [C][R] ----------------
__global__ __launch_bounds__(256) void k_transpose_bf16(
    const float* __restrict__ src, u16* __restrict__ dst, int R, int C) {
  __shared__ float tile[32][33];
  int bx = blockIdx.x * 32, by = blockIdx.y * 32;
  int tx = threadIdx.x & 31, ty = threadIdx.x >> 5;
#pragma unroll
  for (int i = 0; i < 4; ++i) {
    int r = ty + i * 8;
    tile[r][tx] = src[(size_t)(by + r) * C + (bx + tx)];
  }
  __syncthreads();
#pragma unroll
  for (int i = 0; i < 4; ++i) {
    int c = ty + i * 8;
    dst[(size_t)(bx + c) * R + (by + tx)] = f2bf(tile[tx][c]);
  }
}

__global__ __launch_bounds__(256) void k_transpose4(
    const float* __restrict__ s0, const float* __restrict__ s1,
    const float* __restrict__ s2, const float* __restrict__ s3,
    u16* __restrict__ d0, u16* __restrict__ d1,
    u16* __restrict__ d2, u16* __restrict__ d3) {
  __shared__ float tile[32][33];
  const float* src = blockIdx.z == 0 ? s0 : blockIdx.z == 1 ? s1 : blockIdx.z == 2 ? s2 : s3;
  u16* dst = blockIdx.z == 0 ? d0 : blockIdx.z == 1 ? d1 : blockIdx.z == 2 ? d2 : d3;
  int bx = blockIdx.x * 32, by = blockIdx.y * 32;
  int tx = threadIdx.x & 31, ty = threadIdx.x >> 5;
#pragma unroll
  for (int i = 0; i < 4; ++i) {
    int r = ty + i * 8;
    tile[r][tx] = src[(size_t)(by + r) * 512 + (bx + tx)];
  }
  __syncthreads();
#pragma unroll
  for (int i = 0; i < 4; ++i) {
    int c = ty + i * 8;
    dst[(size_t)(bx + c) * 512 + (by + tx)] = f2bf(tile[tx][c]);
  }
}

__global__ __launch_bounds__(256) void k_concat3(
    const float* __restrict__ a, const float* __restrict__ b,
    const float* __restrict__ c, float* __restrict__ o) {
  int i = blockIdx.x * 256 + threadIdx.x;  // grid 6
  if (i < 512) o[i] = a[i];
  else if (i < 1024) o[i] = b[i - 512];
  else o[i] = c[i - 1024];
}

// ---------------- LayerNorm f32 -> bf16, D=512, one wave per row ----------------
__global__ __launch_bounds__(256) void k_layernorm_bf16(
    const float* __restrict__ x, const float* __restrict__ g,
    const float* __restrict__ b, u16* __restrict__ out) {
  int tid = threadIdx.x, wid = tid >> 6, lane = tid & 63;
  int row = blockIdx.x * 4 + wid;
  const float* xr = x + (size_t)row * DMODEL;
  float4 v0 = *(const float4*)(xr + lane * 4);
  float4 v1 = *(const float4*)(xr + 256 + lane * 4);
  float s = v0.x + v0.y + v0.z + v0.w + v1.x + v1.y + v1.z + v1.w;
  float sq = v0.x * v0.x + v0.y * v0.y + v0.z * v0.z + v0.w * v0.w +
             v1.x * v1.x + v1.y * v1.y + v1.z * v1.z + v1.w * v1.w;
#pragma unroll
  for (int m = 1; m < 64; m <<= 1) {
    s += __shfl_xor(s, m);
    sq += __shfl_xor(sq, m);
  }
  float mean = s * (1.0f / DMODEL);
  float rstd = rsqrtf(sq * (1.0f / DMODEL) - mean * mean + 1e-5f);
  float4 ga = *(const float4*)(g + lane * 4);
  float4 gb = *(const float4*)(g + 256 + lane * 4);
  float4 ba = *(const float4*)(b + lane * 4);
  float4 bb = *(const float4*)(b + 256 + lane * 4);
  ushort4 o0, o1;
  o0.x = f2bf((v0.x - mean) * rstd * ga.x + ba.x);
  o0.y = f2bf((v0.y - mean) * rstd * ga.y + ba.y);
  o0.z = f2bf((v0.z - mean) * rstd * ga.z + ba.z);
  o0.w = f2bf((v0.w - mean) * rstd * ga.w + ba.w);
  o1.x = f2bf((v1.x - mean) * rstd * gb.x + bb.x);
  o1.y = f2bf((v1.y - mean) * rstd * gb.y + bb.y);
  o1.z = f2bf((v1.z - mean) * rstd * gb.z + bb.z);
  o1.w = f2bf((v1.w - mean) * rstd * gb.w + bb.w);
  u16* op = out + (size_t)row * DMODEL;
  *(ushort4*)(op + lane * 4) = o0;
  *(ushort4*)(op + 256 + lane * 4) = o1;
}

// ---------------- local attention: one wave per token ----------------
__global__ __launch_bounds__(256) void k_attn(
    const u16* __restrict__ q, const u16* __restrict__ kk,
    const u16* __restrict__ vv, const int* __restrict__ gpos,
    u16* __restrict__ out) {
  int tid = threadIdx.x, wid = tid >> 6, lane = tid & 63;
  int n = blockIdx.x * 4 + wid;
  int px = gpos[2 * n], py = gpos[2 * n + 1];
  float qf[8];
  unpack8(*(const uint4*)(q + (size_t)n * DMODEL + lane * 8), qf);
  float sc[24];
  int nid[24];
  bool ok[24];
#pragma unroll
  for (int j = 0; j < 24; ++j) {
    int jj = j < 12 ? j : j + 1;           // skip (0,0)
    int dx = jj / 5 - 2, dy = jj % 5 - 2;
    int nx = px + dx, ny = py + dy;
    bool val = (nx >= 0) && (nx < GRID_G) && (ny >= 0) && (ny < GRID_G);
    int id = val ? nx * GRID_G + ny : 0;
    ok[j] = val;
    nid[j] = id;
    float kf[8];
    unpack8(*(const uint4*)(kk + (size_t)id * DMODEL + lane * 8), kf);
    float p = 0.f;
#pragma unroll
    for (int e = 0; e < 8; ++e) p += qf[e] * kf[e];
#pragma unroll
    for (int m = 1; m < 64; m <<= 1) p += __shfl_xor(p, m);
    sc[j] = p * 0.04419417382415922f;  // 1/sqrt(512)
  }
  float mx = -3.0e38f;
#pragma unroll
  for (int j = 0; j < 24; ++j)
    if (ok[j]) mx = fmaxf(mx, sc[j]);
  float wsum = 0.f, w[24];
#pragma unroll
  for (int j = 0; j < 24; ++j) {
    w[j] = ok[j] ? expf(sc[j] - mx) : 0.f;
    wsum += w[j];
  }
  float inv = 1.0f / wsum;
  float acc[8] = {0, 0, 0, 0, 0, 0, 0, 0};
#pragma unroll
  for (int j = 0; j < 24; ++j) {
    float vf[8];
    unpack8(*(const uint4*)(vv + (size_t)nid[j] * DMODEL + lane * 8), vf);
    float wj = w[j];
#pragma unroll
    for (int e = 0; e < 8; ++e) acc[e] += wj * vf[e];
  }
  uint4 o;
  o.x = (u32)f2bf(acc[0] * inv) | ((u32)f2bf(acc[1] * inv) << 16);
  o.y = (u32)f2bf(acc[2] * inv) | ((u32)f2bf(acc[3] * inv) << 16);
  o.z = (u32)f2bf(acc[4] * inv) | ((u32)f2bf(acc[5] * inv) << 16);
  o.w = (u32)f2bf(acc[6] * inv) | ((u32)f2bf(acc[7] * inv) << 16);
  *(uint4*)(out + (size_t)n * DMODEL + lane * 8) = o;
}

// ============ MFMA GEMM: 128x128, BK=64, dbuf, COUNTED vmcnt (T4) ============
// Per tile: STAGE(next)[8 loads/wave] -> s_waitcnt vmcnt(8) -> s_barrier ->
// COMPUTE -> s_barrier. Prefetch stays in flight across barriers; only the
// tail drains to 0. Second barrier protects WAR (stage t+2 vs reads of t).
// EPI 1: out_f32 = res + acc + bias
// EPI 2: out_bf16 = gelu(acc + bias)
// EPI 3: QKV-fused: out_bf16[seg][row][col&511], seg = col>>9
#define BARR { __builtin_amdgcn_s_barrier(); __builtin_amdgcn_sched_barrier(0); }
#define WAIT8 asm volatile("s_waitcnt vmcnt(8)" ::: "memory");
#define WAIT0 asm volatile("s_waitcnt vmcnt(0)" ::: "memory");

template <int EPI>
__global__ __launch_bounds__(256, 2) void k_gemm(
    const u16* __restrict__ A, const u16* __restrict__ Bt,
    const float* __restrict__ bias, const float* __restrict__ res,
    float* __restrict__ outF, u16* __restrict__ outB,
    int M, int N, int K, int tiles_n) {
  __shared__ u16 lds[32768];  // 64KB: buf0 {A:0, B:8192}, buf1 {A:16384, B:24576}
  const int t = threadIdx.x, wid = t >> 6, lane = t & 63;
  const int nwg = gridDim.x, bid = blockIdx.x;
  const int l = ((bid & 7) * (nwg >> 3)) + (bid >> 3);   // XCD-contiguous chunks
  const int bM = (l / tiles_n) * 128, bN = (l % tiles_n) * 128;
  const int wr = wid >> 1, wc = wid & 1, lr = lane & 15, lg = lane >> 4;

  // ---- staging setup (computed ONCE; loop adds uniform koff) ----
  const int rs = lane >> 3;             // row-in-8-group
  const int cl = (lane & 7) ^ rs;       // logical chunk (inverse swizzle)
  const u16* gA[4];
  const u16* gB[4];
  int dstL[4];
#pragma unroll
  for (int j = 0; j < 4; ++j) {
    int r = wid * 32 + j * 8 + rs;
    gA[j] = A + (size_t)(bM + r) * K + cl * 8;
    gB[j] = Bt + (size_t)(bN + r) * K + cl * 8;
    dstL[j] = wid * 2048 + j * 512;
  }

#define STAGE(BUF, KOFF)                                                              \
  {                                                                                   \
    _Pragma("unroll") for (int j = 0; j < 4; ++j) {                                   \
      __builtin_amdgcn_global_load_lds(                                               \
          (const __attribute__((address_space(1))) void*)(gA[j] + (KOFF)),            \
          (__attribute__((address_space(3))) void*)(lds + (BUF)*16384 + dstL[j]),     \
          16, 0, 0);                                                                  \
      __builtin_amdgcn_global_load_lds(                                               \
          (const __attribute__((address_space(1))) void*)(gB[j] + (KOFF)),            \
          (__attribute__((address_space(3))) void*)(lds + (BUF)*16384 + 8192 + dstL[j]), \
          16, 0, 0);                                                                  \
    }                                                                                 \
  }

  // ---- ds_read base offsets (u16 units), mt/nt strides are immediates ----
  const int offA0 = (wr * 64 + lr) * 64 + ((0 + lg) ^ (lr & 7)) * 8;
  const int offA1 = (wr * 64 + lr) * 64 + ((4 + lg) ^ (lr & 7)) * 8;
  const int offB0 = (wc * 64 + lr) * 64 + ((0 + lg) ^ (lr & 7)) * 8;
  const int offB1 = (wc * 64 + lr) * 64 + ((4 + lg) ^ (lr & 7)) * 8;

  f32x4 acc[4][4];
#pragma unroll
  for (int i = 0; i < 4; ++i)
#pragma unroll
    for (int j = 0; j < 4; ++j) acc[i][j] = (f32x4){0.f, 0.f, 0.f, 0.f};

#define COMPUTE(BUF)                                                                  \
  {                                                                                   \
    _Pragma("unroll") for (int ks = 0; ks < 2; ++ks) {                                \
      const int oa = (BUF)*16384 + (ks ? offA1 : offA0);                              \
      const int ob = (BUF)*16384 + 8192 + (ks ? offB1 : offB0);                       \
      bf16x8 af[4], bfr[4];                                                           \
      _Pragma("unroll") for (int mt = 0; mt < 4; ++mt)                                \
          af[mt] = __builtin_bit_cast(bf16x8, *(const uint4*)(lds + oa + mt * 1024)); \
      _Pragma("unroll") for (int nt = 0; nt < 4; ++nt)                                \
          bfr[nt] = __builtin_bit_cast(bf16x8, *(const uint4*)(lds + ob + nt * 1024));\
      _Pragma("unroll") for (int mt = 0; mt < 4; ++mt)                                \
          _Pragma("unroll") for (int nt = 0; nt < 4; ++nt)                            \
              acc[mt][nt] = __builtin_amdgcn_mfma_f32_16x16x32_bf16(                  \
                  af[mt], bfr[nt], acc[mt][nt], 0, 0, 0);                             \
    }                                                                                 \
  }

  const int nk = K >> 6;  // even for all our K (512, 2048)
  STAGE(0, 0);
  int koff = 64;
  for (int tt = 0; tt < nk; tt += 2) {
    if (tt + 1 < nk) { STAGE(1, koff); WAIT8 } else { WAIT0 }
    BARR;           // tile tt landed collectively; prefetch tt+1 in flight
    COMPUTE(0);
    BARR;           // WAR: reads of buf0 done before next STAGE(0,...)
    if (tt + 2 < nk) { STAGE(0, koff + 64); WAIT8 } else { WAIT0 }
    BARR;
    COMPUTE(1);
    BARR;
    koff += 128;
  }
#undef STAGE
#undef COMPUTE

  // epilogue: D row = lg*4 + r, col = lr (verified layout)
#pragma unroll
  for (int mt = 0; mt < 4; ++mt) {
#pragma unroll
    for (int nt = 0; nt < 4; ++nt) {
      int col = bN + wc * 64 + nt * 16 + lr;
      float bc = bias[col];
      int row0 = bM + wr * 64 + mt * 16 + lg * 4;
#pragma unroll
      for (int r = 0; r < 4; ++r) {
        float val = acc[mt][nt][r] + bc;
        if constexpr (EPI == 1) {
          size_t off = (size_t)(row0 + r) * N + col;
          outF[off] = res[off] + val;
        } else if constexpr (EPI == 2) {
          size_t off = (size_t)(row0 + r) * N + col;
          outB[off] = f2bf(gelu_fast(val));
        } else {  // EPI 3: segmented QKV
          int seg = col >> 9;
          size_t off = (size_t)seg * ((size_t)NTOK * DMODEL) +
                       (size_t)(row0 + r) * DMODEL + (col & 511);
          outB[off] = f2bf(val);
        }
      }
    }
  }
}

// ---------------- workspace layout ----------------
extern "C" void kernel_launch(void* const* d_in, const int* in_sizes, int n_in,
                              void* d_out, int out_size, void* d_ws, size_t ws_size,
                              hipStream_t stream) {
  const float* x = (const float*)d_in[0];
  const int* gpos = (const int*)d_in[1];
  const float* Wq = (const float*)d_in[2];
  const float* bq = (const float*)d_in[3];
  const float* Wk = (const float*)d_in[4];
  const float* bk = (const float*)d_in[5];
  const float* Wv = (const float*)d_in[6];
  const float* bv = (const float*)d_in[7];
  const float* Wo = (const float*)d_in[8];
  const float* bo = (const float*)d_in[9];
  const float* g1 = (const float*)d_in[10];
  const float* b1 = (const float*)d_in[11];
  const float* g2 = (const float*)d_in[12];
  const float* b2 = (const float*)d_in[13];
  const float* W1 = (const float*)d_in[14];
  const float* bf1 = (const float*)d_in[15];
  const float* W2 = (const float*)d_in[16];
  const float* bf2 = (const float*)d_in[17];
  float* out = (float*)d_out;
  char* ws = (char*)d_ws;

  constexpr size_t SZ_W512 = (size_t)512 * 512 * 2;
  constexpr size_t SZ_W2048 = (size_t)512 * 2048 * 2;
  constexpr size_t SZ_ACT = (size_t)NTOK * 512 * 2;

  u16* WQT = (u16*)(ws + 0);                 // [1536][512] contiguous (Q,K,V)
  u16* WKT = (u16*)(ws + SZ_W512);
  u16* WVT = (u16*)(ws + 2 * SZ_W512);
  u16* WOT = (u16*)(ws + 3 * SZ_W512);
  u16* W1T = (u16*)(ws + 4 * SZ_W512);
  u16* W2T = (u16*)(ws + 4 * SZ_W512 + SZ_W2048);
  float* BCAT = (float*)(ws + 4 * SZ_W512 + 2 * SZ_W2048);  // 1536 f32
  char* actbase = ws + 4 * SZ_W512 + 2 * SZ_W2048 + 6144;
  u16* H = (u16*)(actbase);
  u16* Q = (u16*)(actbase + SZ_ACT);         // Q,K,V contiguous (fused epilogue)
  u16* KB = (u16*)(actbase + 2 * SZ_ACT);
  u16* VB = (u16*)(actbase + 3 * SZ_ACT);
  u16* H2 = (u16*)(actbase + 4 * SZ_ACT);
  u16* U = (u16*)(actbase);                  // [NTOK][2048] overlaps H,Q,K,V

  // weight prep
  k_transpose4<<<dim3(16, 16, 4), 256, 0, stream>>>(Wq, Wk, Wv, Wo, WQT, WKT, WVT, WOT);
  k_transpose_bf16<<<dim3(64, 16), 256, 0, stream>>>(W1, W1T, 512, 2048);
  k_transpose_bf16<<<dim3(16, 64), 256, 0, stream>>>(W2, W2T, 2048, 512);
  k_concat3<<<6, 256, 0, stream>>>(bq, bk, bv, BCAT);

  // LN1: x -> h
  k_layernorm_bf16<<<NTOK / 4, 256, 0, stream>>>(x, g1, b1, H);

  // fused QKV: [NTOK,1536] = H @ [Wq|Wk|Wv]^T  (grid 72*12=864)
  k_gemm<3><<<864, 256, 0, stream>>>(H, WQT, BCAT, nullptr, nullptr, Q, NTOK, 1536, 512, 12);

  // local attention -> H (reuse)
  k_attn<<<NTOK / 4, 256, 0, stream>>>(Q, KB, VB, gpos, H);

  // y = x + attn @ Wo + bo  (f32, in d_out; grid 72*4=288)
  k_gemm<1><<<288, 256, 0, stream>>>(H, WOT, bo, x, out, nullptr, NTOK, 512, 512, 4);

  // LN2: y -> h2
  k_layernorm_bf16<<<NTOK / 4, 256, 0, stream>>>(out, g2, b2, H2);

  // u = gelu(h2 @ W1 + bf1)  (grid 72*16=1152)
  k_gemm<2><<<1152, 256, 0, stream>>>(H2, W1T, bf1, nullptr, nullptr, U, NTOK, 2048, 512, 16);

  // out = y + u @ W2 + bf2  (in-place residual; grid 288)
  k_gemm<1><<<288, 256, 0, stream>>>(U, W2T, bf2, out, out, nullptr, NTOK, 512, 2048, 4);
}